// Round 1
// baseline (572.261 us; speedup 1.0000x reference)
//
#include <hip/hip_runtime.h>
#include <hip/hip_bf16.h>

// ManifoldHyperConnections: T=4096 rows, K=16384, 24 output cols + sumsq,
// then per-row 4x4 Sinkhorn (400 iters).
//
// Kernel 1 (gemv_part): lane-per-row split-K GEMV. Each lane holds 25 fp32
// accumulators; weight rows are wave-uniform -> scalar loads; x is read as
// 4x float4 from one 64B line per lane per chunk (L1 absorbs the 16B/64B
// granularity). Partials combined with fp32 atomicAdd into d_ws (400 KB).
// Kernel 2 (sinkhorn_epilogue): thread-per-row activations + 400 Sinkhorn
// iterations fully in registers, fast v_rcp.

#define TROWS 4096
#define KDIM  16384
#define NOUT  24
#define KC    64                 // split-K chunks
#define KPER  (KDIM / KC)        // 256 k per wave
#define CITER (KPER / 16)        // 16 chunks of 16 floats

__device__ __forceinline__ float fast_rcp(float x) {
#if defined(__has_builtin)
#if __has_builtin(__builtin_amdgcn_rcpf)
    return __builtin_amdgcn_rcpf(x);
#else
    return 1.0f / x;
#endif
#else
    return 1.0f / x;
#endif
}

__device__ __forceinline__ float fast_rsqrt(float x) {
#if defined(__has_builtin)
#if __has_builtin(__builtin_amdgcn_rsqf)
    return __builtin_amdgcn_rsqf(x);
#else
    return rsqrtf(x);
#endif
#else
    return rsqrtf(x);
#endif
}

__global__ __launch_bounds__(256) void gemv_part(const float* __restrict__ x,
                                                 const float* __restrict__ w,
                                                 float* __restrict__ hacc) {
    const int wave = blockIdx.x * 4 + (threadIdx.x >> 6);
    const int lane = threadIdx.x & 63;
    const int rg   = wave & 63;   // row group (64 rows)
    const int kc   = wave >> 6;   // k chunk
    const int row  = rg * 64 + lane;
    const int k0   = kc * KPER;

    const float4* xp = (const float4*)(x + (size_t)row * KDIM + k0);
    const float*  wp = w + (size_t)k0 * NOUT;

    float acc[NOUT];
#pragma unroll
    for (int j = 0; j < NOUT; ++j) acc[j] = 0.0f;
    float ss = 0.0f;

    float4 c0 = xp[0], c1 = xp[1], c2 = xp[2], c3 = xp[3];

#pragma unroll 1
    for (int c = 0; c < CITER; ++c) {
        // prefetch next 64B chunk (clamped on last iter to stay in-bounds)
        const float4* np4 = (c + 1 < CITER) ? (xp + 4) : xp;
        float4 n0 = np4[0], n1 = np4[1], n2 = np4[2], n3 = np4[3];

        const float* wk = wp + c * 16 * NOUT;   // wave-uniform -> s_load
        const float xs[16] = {c0.x, c0.y, c0.z, c0.w,
                              c1.x, c1.y, c1.z, c1.w,
                              c2.x, c2.y, c2.z, c2.w,
                              c3.x, c3.y, c3.z, c3.w};
#pragma unroll
        for (int u = 0; u < 16; ++u) {
            const float xe = xs[u];
            ss = fmaf(xe, xe, ss);
            const float* wr = wk + u * NOUT;
#pragma unroll
            for (int j = 0; j < NOUT; ++j) acc[j] = fmaf(wr[j], xe, acc[j]);
        }
        c0 = n0; c1 = n1; c2 = n2; c3 = n3;
        xp = np4;
    }

    // combine split-K partials; layout hacc[j][row] (coalesced across lanes)
#pragma unroll
    for (int j = 0; j < NOUT; ++j)
        atomicAdd(hacc + (size_t)j * TROWS + row, acc[j]);
    atomicAdd(hacc + (size_t)NOUT * TROWS + row, ss);
}

__global__ __launch_bounds__(64) void sinkhorn_epilogue(const float* __restrict__ hacc,
                                                        const float* __restrict__ bias,
                                                        const float* __restrict__ alpha,
                                                        float* __restrict__ out) {
    const int row = blockIdx.x * 64 + threadIdx.x;

    float h[25];
#pragma unroll
    for (int j = 0; j < 25; ++j) h[j] = hacc[(size_t)j * TROWS + row];

    const float r_inv = fast_rsqrt(h[24] * (1.0f / (float)KDIM));
    const float a0 = alpha[0], a1 = alpha[1], a2 = alpha[2];

    // h_pre / h_post
#pragma unroll
    for (int i = 0; i < 4; ++i) {
        const float zpre = fmaf(r_inv * a0, h[i], bias[i]);
        out[(size_t)row * 4 + i] = fast_rcp(1.0f + expf(-zpre));
        const float zpo = fmaf(r_inv * a1, h[4 + i], bias[4 + i]);
        out[(size_t)16384 + (size_t)row * 4 + i] = 2.0f * fast_rcp(1.0f + expf(-zpo));
    }

    // E = exp(r_inv*a2*h_res + bias), row-major 4x4
    float E[16];
#pragma unroll
    for (int t = 0; t < 16; ++t)
        E[t] = expf(fmaf(r_inv * a2, h[8 + t], bias[8 + t]));

    float u0 = 1.0f, u1 = 1.0f, u2 = 1.0f, u3 = 1.0f;
    float v0 = 1.0f, v1 = 1.0f, v2 = 1.0f, v3 = 1.0f;

#pragma unroll 1
    for (int it = 0; it < 400; ++it) {
        float s0 = fmaf(E[0],  v0, fmaf(E[1],  v1, fmaf(E[2],  v2, E[3]  * v3)));
        float s1 = fmaf(E[4],  v0, fmaf(E[5],  v1, fmaf(E[6],  v2, E[7]  * v3)));
        float s2 = fmaf(E[8],  v0, fmaf(E[9],  v1, fmaf(E[10], v2, E[11] * v3)));
        float s3 = fmaf(E[12], v0, fmaf(E[13], v1, fmaf(E[14], v2, E[15] * v3)));
        u0 = fast_rcp(s0 + 1e-12f);
        u1 = fast_rcp(s1 + 1e-12f);
        u2 = fast_rcp(s2 + 1e-12f);
        u3 = fast_rcp(s3 + 1e-12f);
        float t0 = fmaf(E[0], u0, fmaf(E[4], u1, fmaf(E[8],  u2, E[12] * u3)));
        float t1 = fmaf(E[1], u0, fmaf(E[5], u1, fmaf(E[9],  u2, E[13] * u3)));
        float t2 = fmaf(E[2], u0, fmaf(E[6], u1, fmaf(E[10], u2, E[14] * u3)));
        float t3 = fmaf(E[3], u0, fmaf(E[7], u1, fmaf(E[11], u2, E[15] * u3)));
        v0 = fast_rcp(t0 + 1e-12f);
        v1 = fast_rcp(t1 + 1e-12f);
        v2 = fast_rcp(t2 + 1e-12f);
        v3 = fast_rcp(t3 + 1e-12f);
    }

    const size_t ob = 32768 + (size_t)row * 16;
    out[ob + 0]  = u0 * E[0]  * v0;
    out[ob + 1]  = u0 * E[1]  * v1;
    out[ob + 2]  = u0 * E[2]  * v2;
    out[ob + 3]  = u0 * E[3]  * v3;
    out[ob + 4]  = u1 * E[4]  * v0;
    out[ob + 5]  = u1 * E[5]  * v1;
    out[ob + 6]  = u1 * E[6]  * v2;
    out[ob + 7]  = u1 * E[7]  * v3;
    out[ob + 8]  = u2 * E[8]  * v0;
    out[ob + 9]  = u2 * E[9]  * v1;
    out[ob + 10] = u2 * E[10] * v2;
    out[ob + 11] = u2 * E[11] * v3;
    out[ob + 12] = u3 * E[12] * v0;
    out[ob + 13] = u3 * E[13] * v1;
    out[ob + 14] = u3 * E[14] * v2;
    out[ob + 15] = u3 * E[15] * v3;
}

extern "C" void kernel_launch(void* const* d_in, const int* in_sizes, int n_in,
                              void* d_out, int out_size, void* d_ws, size_t ws_size,
                              hipStream_t stream) {
    const float* x     = (const float*)d_in[0];
    const float* w     = (const float*)d_in[1];
    const float* bias  = (const float*)d_in[2];
    const float* alpha = (const float*)d_in[3];
    float* out  = (float*)d_out;
    float* hacc = (float*)d_ws;   // 25 * 4096 floats = 400 KB

    hipMemsetAsync(hacc, 0, (size_t)(NOUT + 1) * TROWS * sizeof(float), stream);
    gemv_part<<<dim3((64 * KC) / 4), dim3(256), 0, stream>>>(x, w, hacc);
    sinkhorn_epilogue<<<dim3(TROWS / 64), dim3(64), 0, stream>>>(hacc, bias, alpha, out);
}